// Round 2
// 279.539 us; speedup vs baseline: 1.1209x; 1.1209x over previous
//
#include <hip/hip_runtime.h>
#include <cstdint>
#include <cstddef>

#define T_LEN 8192
#define BATCH 64
#define HID   10
#define CH    66
#define EEG   64
#define SM_STRIDE 8384   // 192-entry zero pad + 8192 live, per batch (16B-aligned stride)

// ---------------------------------------------------------------------------
// K1: front projection  y[b][h][t] = b_front[h] + sum_c x[b,0,c+1,t]*w_front[h,c]
// grid (8, 64), block 256, 4 t per thread (float4 loads, float4 coalesced stores).
// Memory-floor bound (~134 MB x read, L3 cold each iter). Unchanged.
// ---------------------------------------------------------------------------
__global__ void k_front(const float* __restrict__ x, const float* __restrict__ wf_g,
                        const float* __restrict__ bf_g, float* __restrict__ y) {
    __shared__ float wf[EEG][HID];   // wf[c][h]
    __shared__ float bf[HID];
    int tid = threadIdx.x;
    for (int i = tid; i < EEG * HID; i += 256) {
        int h = i / EEG, c = i % EEG;      // w_front layout (H, C)
        wf[c][h] = wf_g[i];
    }
    if (tid < HID) bf[tid] = bf_g[tid];
    __syncthreads();

    int b = blockIdx.y;
    int t4 = (blockIdx.x * 256 + tid) * 4;
    const float* xb = x + ((size_t)b * CH + 1) * T_LEN + t4;   // skip aud channel 0
    float acc[4][HID];
#pragma unroll
    for (int j = 0; j < 4; ++j)
#pragma unroll
        for (int h = 0; h < HID; ++h) acc[j][h] = bf[h];
#pragma unroll 4
    for (int c = 0; c < EEG; ++c) {
        float4 xv = *(const float4*)(xb + (size_t)c * T_LEN);
#pragma unroll
        for (int h = 0; h < HID; ++h) {
            float w = wf[c][h];
            acc[0][h] = fmaf(xv.x, w, acc[0][h]);
            acc[1][h] = fmaf(xv.y, w, acc[1][h]);
            acc[2][h] = fmaf(xv.z, w, acc[2][h]);
            acc[3][h] = fmaf(xv.w, w, acc[3][h]);
        }
    }
    float* yo = y + (size_t)b * HID * T_LEN + t4;   // [b][h][t]: lane-consecutive t4
#pragma unroll
    for (int h = 0; h < HID; ++h)
        *(float4*)(yo + (size_t)h * T_LEN) =
            make_float4(acc[0][h], acc[1][h], acc[2][h], acc[3][h]);
}

// ---------------------------------------------------------------------------
// K2: front LIF. 128 chunks of 64 live steps, warm 32 (same 0.25^32 ~ 5e-20
// exactness as before). grid 2048 (= 128 chunks x 16 batch-quads) -> 8 waves/CU
// (was 2), 3-deep float4 prefetch ring (was 2) to cover ~L3 latency.
// Block-id mapping puts each block on the XCD whose L2 holds its y t-slice
// (writer K1 block (tx,b) lands on XCD tx; here id&7 == c>>4 == tx).
// Chunk-0 blocks also zero the 192-entry smask pad.
// ---------------------------------------------------------------------------
__global__ __launch_bounds__(64) void k_flif(const float* __restrict__ y,
                                             unsigned short* __restrict__ smask) {
    int id = blockIdx.x;
    int c  = (id & 7) * 16 + ((id >> 3) & 15);  // chunk 0..127; id%8 == c>>4 (writer XCD)
    int bq = id >> 7;                            // batch quad 0..15
    int lane = threadIdx.x;
    int g = lane >> 4, h = lane & 15;
    int b = bq * 4 + g;
    int hh = h < HID ? h : HID - 1;  // inactive lanes duplicate h=9 (same addr -> merged)

    if (c == 0) {                    // zero the pad region for this block's 4 batches
        for (int i = lane; i < 4 * 96; i += 64) {
            int j = i / 96, w = i % 96;
            ((unsigned*)(smask + (size_t)(bq * 4 + j) * SM_STRIDE))[w] = 0u;
        }
    }

    int t0 = c * 64;
    int ts = t0 - 32; if (ts < 0) ts = 0;
    int nf = (t0 + 64 - ts) >> 2;   // # float4 steps (16 for c=0, else 24)
    const float4* yb = (const float4*)(y + ((size_t)b * HID + hh) * T_LEN + ts);

    float4 A = yb[0], B = yb[1], C = yb[2];
    float u = 0.f, o = 0.f;
    unsigned short* smb = smask + (size_t)b * SM_STRIDE + 192;
    for (int f = 0; f < nf; ++f) {
        int nx = f + 3; if (nx > nf - 1) nx = nf - 1;
        float4 D = yb[nx];
        float vv[4] = {A.x, A.y, A.z, A.w};
        int tb = ts + f * 4;
#pragma unroll
        for (int k = 0; k < 4; ++k) {
            u = (o > 0.5f) ? vv[k] : fmaf(0.25f, u, vv[k]);   // 0.25*u exact
            bool sp = (u > 0.2f);
            o = sp ? 1.0f : 0.0f;
            unsigned long long bal = __ballot(sp);
            int t = tb + k;
            if (t >= t0 && h == 0)
                smb[t] = (unsigned short)((bal >> (g * 16)) & 0x3FFull);
        }
        A = B; B = C; C = D;
    }
}

// ---------------------------------------------------------------------------
// K3: LSNN scan + classifier. 128 chunks x 64 live steps, warm 192 (zero pad
// -> uniform 256-step loop). Structure as before EXCEPT: the 2-level
// subset-sum table (2 ds_read + add per lookup) is now expanded ONCE per
// block into a direct 1024x22 table D (88 KB LDS) -> every rec/X/P lookup is
// a SINGLE ds_read_b32. Rationale: previous version issued ~4.7
// ds_read_b32/step/wave; at 8 waves/CU that exceeds the ~0.17 instr/cyc LDS
// throughput ceiling (5.8 cyc/ds_read_b32) -> LDS-throughput-bound. Now
// ~2.34/step, below the ceiling; chain also loses one dependent add.
// D-expansion is bit-exact: same two f32 adds, hoisted out of the loop.
// Blocks are 8 waves (512 thr, 32 units) so 94 KB LDS still leaves all 2048
// units co-resident: grid 256 = exactly 1 block/CU (2x94KB > 160KB).
// ---------------------------------------------------------------------------
__global__ __launch_bounds__(512) void k_lsnn(
    const unsigned short* __restrict__ smask,
    const float* __restrict__ w_in, const float* __restrict__ w_rec,
    const float* __restrict__ w_cls, const float* __restrict__ b_cls,
    float* __restrict__ out) {
    extern __shared__ float LDSBUF[];
    float* T = LDSBUF;          // [1536]: [hi*768 + m*24 + role], roles 0-9 w_in,
                                //         10-11 w_cls, 12-21 w_rec, 22-23 zero
    float* D = LDSBUF + 1536;   // [1024*22]: D[z*22+role] = full 10-bit subset sum
    int tid = threadIdx.x;
    for (int i = tid; i < 1536; i += 512) {
        int hi = i / 768;
        int rem = i - hi * 768;
        int m = rem / 24, role = rem - m * 24;
        float s = 0.f;
        if (role < 22) {
            const float* wrow = (role < 10) ? (w_in + role * HID)
                              : (role < 12) ? (w_cls + (role - 10) * HID)
                                            : (w_rec + (role - 12) * HID);
#pragma unroll
            for (int j = 0; j < 5; ++j)
                if (m & (1u << j)) s += wrow[hi * 5 + j];
        }
        T[i] = s;
    }
    __syncthreads();
    for (int i = tid; i < 1024 * 22; i += 512) {
        int z = i / 22, role = i - z * 22;
        D[i] = T[(z & 31) * 24 + role] + T[768 + (z >> 5) * 24 + role];
    }
    __syncthreads();

    int lane = tid & 63;
    int q = lane >> 4;                 // unit-in-wave 0..3
    int r = lane & 15;                 // role: 0..9 hidden, 10..11 cls, 12..15 shadow
    int rr = r < 12 ? r : 11;          // X/P table role (shadows duplicate 11)
    int rrec = 12 + (r < HID ? r : 9); // rec table role (cls/shadows dup row 9, unused)
    int shq = q * 16;
    int id = blockIdx.x * 32 + (tid >> 4);   // 256*32 = 8192 units, no tail
    int b = id >> 7, chunk = id & 127;

    float bcl = (r == 10 || r == 11) ? b_cls[r - HID] : 0.f;

    const unsigned short* sm = smask + (size_t)b * SM_STRIDE + (size_t)chunk * 64;

    auto xlook = [&](const uint4& mv, float* X) {
        unsigned hw[8] = { mv.x & 0x3FFu, (mv.x >> 16) & 0x3FFu,
                           mv.y & 0x3FFu, (mv.y >> 16) & 0x3FFu,
                           mv.z & 0x3FFu, (mv.z >> 16) & 0x3FFu,
                           mv.w & 0x3FFu, (mv.w >> 16) & 0x3FFu };
#pragma unroll
        for (int u = 0; u < 8; ++u)
            X[u] = D[hw[u] * 22 + rr];
    };

    // 4-deep mask prefetch ring
    uint4 mB = *(const uint4*)(sm + 8);
    uint4 mC = *(const uint4*)(sm + 16);
    uint4 mD = *(const uint4*)(sm + 24);
    float Xc[8], Xn[8], Pc[8], Pn[8];
    { uint4 m0 = *(const uint4*)(sm); xlook(m0, Xc); }
#pragma unroll
    for (int u = 0; u < 8; ++u) { Pc[u] = 0.f; Pn[u] = 0.f; }

    float v = 0.f, cur = 0.f;
    unsigned zmask = 0;
    float uc = 0.f, oc = 0.f, accs = 0.f;

    for (int gr = 0; gr < 32; ++gr) {
        int nb = gr + 4; if (nb > 31) nb = 31;
        uint4 mE = *(const uint4*)(sm + (size_t)nb * 8);
        xlook(mB, Xn);                  // x_in for next group (off-chain, 3 groups slack)
        unsigned zs[8];
#pragma unroll
        for (int u = 0; u < 8; ++u) {
            // rec dot: ONE ds_read from the direct table
            float rec = D[zmask * 22 + rrec];
            float ij = (cur + Xc[u]) + rec;
            float vd = v + 0.1f * (ij - v);     // bit-exact form (matches reference)
            cur = ij - 0.2f * ij;               // bit-exact form
            bool zb = vd > 0.2f;                // b_dec == VTH exactly
            unsigned long long bal = __ballot(zb);
            v = zb ? 0.f : vd;
            zmask = (unsigned)(bal >> shq) & 0x3FFu;
            zs[u] = zmask;
        }
        if (gr >= 21) {                        // classifier-input lookups (batched)
#pragma unroll
            for (int u = 0; u < 8; ++u)
                Pn[u] = D[zs[u] * 22 + rr];
        }
        if (gr >= 22) {                        // classifier LIF for group gr-1
            bool in = (gr >= 25);              // live groups are 24..31
#pragma unroll
            for (int u = 0; u < 8; ++u) {
                float ci = Pc[u] + bcl;
                uc = (oc > 0.5f) ? ci : fmaf(0.25f, uc, ci);
                oc = (uc > 0.2f) ? 1.f : 0.f;
                if (in) accs += oc;
            }
        }
#pragma unroll
        for (int u = 0; u < 8; ++u) { Xc[u] = Xn[u]; Pc[u] = Pn[u]; }
        mB = mC; mC = mD; mD = mE;
    }
    // epilogue: classifier for group 31 (live)
#pragma unroll
    for (int u = 0; u < 8; ++u) {
        float ci = Pc[u] + bcl;
        uc = (oc > 0.5f) ? ci : fmaf(0.25f, uc, ci);
        oc = (uc > 0.2f) ? 1.f : 0.f;
        accs += oc;
    }
    if (r == 10 || r == 11)
        atomicAdd(&out[b * 2 + (r - 10)], accs * (1.0f / 8192.0f));
}

// ---------------------------------------------------------------------------
extern "C" void kernel_launch(void* const* d_in, const int* in_sizes, int n_in,
                              void* d_out, int out_size, void* d_ws, size_t ws_size,
                              hipStream_t stream) {
    const float* x       = (const float*)d_in[0];
    const float* w_front = (const float*)d_in[1];
    const float* b_front = (const float*)d_in[2];
    const float* w_in    = (const float*)d_in[3];
    const float* w_rec   = (const float*)d_in[4];
    const float* w_cls   = (const float*)d_in[5];
    const float* b_cls   = (const float*)d_in[6];
    float* out = (float*)d_out;

    float* y = (float*)d_ws;                                   // 64*10*8192*4 = 20 MB, [b][h][t]
    unsigned short* smask =
        (unsigned short*)((char*)d_ws + (size_t)BATCH * HID * T_LEN * sizeof(float));

    hipMemsetAsync(out, 0, (size_t)out_size * sizeof(float), stream);
    k_front<<<dim3(T_LEN / 1024, BATCH), 256, 0, stream>>>(x, w_front, b_front, y);
    k_flif<<<dim3(2048), 64, 0, stream>>>(y, smask);
    k_lsnn<<<dim3(256), 512, (1536 + 1024 * 22) * sizeof(float), stream>>>(
        smask, w_in, w_rec, w_cls, b_cls, out);
}

// Round 3
// 277.561 us; speedup vs baseline: 1.1289x; 1.0071x over previous
//
#include <hip/hip_runtime.h>
#include <cstdint>
#include <cstddef>

#define T_LEN 8192
#define BATCH 64
#define HID   10
#define CH    66
#define EEG   64
#define SM_STRIDE 8384   // 192-entry zero pad + 8192 live, per batch (16B-aligned stride)
#define TS    1060       // LDS y-tile stride in floats: 1056 live+warm t's + pad;
                         // 1060*4 B = 16B-aligned rows, banks (1060h mod 32) = 4h ->
                         // only free 2-way aliasing on float4 reads (h vs h+8)

// ---------------------------------------------------------------------------
// K12: FUSED front projection + front LIF. Grid (8, 64) = (t-chunk, batch),
// block 256 (4 waves), 45 KB LDS -> 2 blocks/CU, 8 waves/CU.
// Phase A (all 4 waves): y[h][t] = b_front[h] + sum_c x[b,c+1,t]*w_front[h,c]
//   for t in [chunk*1024 - 32, chunk*1024 + 1024) into LDS tile (264 float4
//   groups, same FMA order as the old K1 -> bit-identical y).
// Phase B (each wave): LIF scan over its 256-step quarter, 32-step warm from
//   the LDS tile (0.25^32 ~ 5e-20, same exactness as before), ballot -> smask.
// y NEVER touches global memory: saves ~52 MB HBM round-trip + one kernel
// boundary vs the old k_front + k_flif pair. out-memset folded in (block 0,0).
// ---------------------------------------------------------------------------
__global__ __launch_bounds__(256) void k_front_lif(
    const float* __restrict__ x, const float* __restrict__ wf_g,
    const float* __restrict__ bf_g, unsigned short* __restrict__ smask,
    float* __restrict__ out) {
    __shared__ float wf[EEG][HID];   // wf[c][h]
    __shared__ float bf[HID];
    __shared__ float yt[HID][TS];    // y tile, tile index k <-> t = t0 - 32 + k
    int tid = threadIdx.x;
    for (int i = tid; i < EEG * HID; i += 256) {
        int h = i / EEG, c = i % EEG;      // w_front layout (H, C)
        wf[c][h] = wf_g[i];
    }
    if (tid < HID) bf[tid] = bf_g[tid];

    int chunk = blockIdx.x;          // 0..7 (1024 live t each)
    int b     = blockIdx.y;          // 0..63
    if (chunk == 0) {                // zero the 192-entry smask pad for this batch
        for (int i = tid; i < 96; i += 256)
            ((unsigned*)(smask + (size_t)b * SM_STRIDE))[i] = 0u;
        if (b == 0)                  // fold the out-memset dispatch in here
            for (int i = tid; i < BATCH * 2; i += 256) out[i] = 0.f;
    }
    __syncthreads();

    // ---- Phase A: projection into LDS tile (bit-identical to old K1) ----
    int t0 = chunk * 1024;
    const float* xb = x + ((size_t)b * CH + 1) * T_LEN;   // skip aud channel 0
    for (int g = tid; g < 264; g += 256) {                // 264 float4 groups
        int t = t0 - 32 + 4 * g;
        if (t < 0) continue;         // chunk-0 head: region never read by LIF
        float acc[4][HID];
#pragma unroll
        for (int j = 0; j < 4; ++j)
#pragma unroll
            for (int h = 0; h < HID; ++h) acc[j][h] = bf[h];
        const float* xp = xb + t;
#pragma unroll 4
        for (int c = 0; c < EEG; ++c) {
            float4 xv = *(const float4*)(xp + (size_t)c * T_LEN);
#pragma unroll
            for (int h = 0; h < HID; ++h) {
                float w = wf[c][h];
                acc[0][h] = fmaf(xv.x, w, acc[0][h]);
                acc[1][h] = fmaf(xv.y, w, acc[1][h]);
                acc[2][h] = fmaf(xv.z, w, acc[2][h]);
                acc[3][h] = fmaf(xv.w, w, acc[3][h]);
            }
        }
        int k = 4 * g;
#pragma unroll
        for (int h = 0; h < HID; ++h)
            *(float4*)&yt[h][k] =
                make_float4(acc[0][h], acc[1][h], acc[2][h], acc[3][h]);
    }
    __syncthreads();

    // ---- Phase B: LIF scan, one 256-step quarter per wave ----
    int w    = tid >> 6;             // wave 0..3
    int lane = tid & 63;
    int h    = lane & 15;
    int hh   = h < HID ? h : HID - 1;  // spare lanes duplicate h=9 (bits masked)

    int kliv = 32 + 256 * w;                       // first live tile index
    int wl   = (chunk == 0 && w == 0) ? 0 : 32;    // warm length
    int ks   = kliv - wl;                          // scan start (mult of 4)
    int nf   = (256 + wl) >> 2;                    // float4 steps (64 or 72)
    const float4* yrow = (const float4*)&yt[hh][0];
    int base = ks >> 2;

    unsigned short* smb = smask + (size_t)b * SM_STRIDE + 192 + t0 + 256 * w;
    float u = 0.f, o = 0.f;
    float4 A = yrow[base], B = yrow[base + 1];
    for (int f = 0; f < nf; ++f) {
        int nx = f + 2; if (nx > nf - 1) nx = nf - 1;
        float4 C = yrow[base + nx];
        float vv[4] = {A.x, A.y, A.z, A.w};
        int kb = ks + 4 * f;
#pragma unroll
        for (int k2 = 0; k2 < 4; ++k2) {
            u = (o > 0.5f) ? vv[k2] : fmaf(0.25f, u, vv[k2]);   // 0.25*u exact
            bool sp = (u > 0.2f);
            o = sp ? 1.0f : 0.0f;
            unsigned long long bal = __ballot(sp);
            int k = kb + k2;
            if (k >= kliv && h == 0)
                smb[k - kliv] = (unsigned short)(bal & 0x3FFull);
        }
        A = B; B = C;
    }
}

// ---------------------------------------------------------------------------
// K3: LSNN scan + classifier. 128 chunks x 64 live steps, warm 192 (zero pad
// -> uniform 256-step loop). Direct 1024x22 subset-sum table D (88 KB LDS):
// every rec/X/P lookup is a single ds_read_b32. At its structural latency
// floor: per-step chain zmask->ds_read(~120cy)->add->fma->cmp->ballot ~140cy
// x 256 steps ~ 15 us; VALU-select rec loses at 2 waves/SIMD, more chunks
// lose to the fixed 192 warm. Unchanged from round 2 (verified).
// ---------------------------------------------------------------------------
__global__ __launch_bounds__(512) void k_lsnn(
    const unsigned short* __restrict__ smask,
    const float* __restrict__ w_in, const float* __restrict__ w_rec,
    const float* __restrict__ w_cls, const float* __restrict__ b_cls,
    float* __restrict__ out) {
    extern __shared__ float LDSBUF[];
    float* T = LDSBUF;          // [1536]: [hi*768 + m*24 + role], roles 0-9 w_in,
                                //         10-11 w_cls, 12-21 w_rec, 22-23 zero
    float* D = LDSBUF + 1536;   // [1024*22]: D[z*22+role] = full 10-bit subset sum
    int tid = threadIdx.x;
    for (int i = tid; i < 1536; i += 512) {
        int hi = i / 768;
        int rem = i - hi * 768;
        int m = rem / 24, role = rem - m * 24;
        float s = 0.f;
        if (role < 22) {
            const float* wrow = (role < 10) ? (w_in + role * HID)
                              : (role < 12) ? (w_cls + (role - 10) * HID)
                                            : (w_rec + (role - 12) * HID);
#pragma unroll
            for (int j = 0; j < 5; ++j)
                if (m & (1u << j)) s += wrow[hi * 5 + j];
        }
        T[i] = s;
    }
    __syncthreads();
    for (int i = tid; i < 1024 * 22; i += 512) {
        int z = i / 22, role = i - z * 22;
        D[i] = T[(z & 31) * 24 + role] + T[768 + (z >> 5) * 24 + role];
    }
    __syncthreads();

    int lane = tid & 63;
    int q = lane >> 4;                 // unit-in-wave 0..3
    int r = lane & 15;                 // role: 0..9 hidden, 10..11 cls, 12..15 shadow
    int rr = r < 12 ? r : 11;          // X/P table role (shadows duplicate 11)
    int rrec = 12 + (r < HID ? r : 9); // rec table role (cls/shadows dup row 9, unused)
    int shq = q * 16;
    int id = blockIdx.x * 32 + (tid >> 4);   // 256*32 = 8192 units, no tail
    int b = id >> 7, chunk = id & 127;

    float bcl = (r == 10 || r == 11) ? b_cls[r - HID] : 0.f;

    const unsigned short* sm = smask + (size_t)b * SM_STRIDE + (size_t)chunk * 64;

    auto xlook = [&](const uint4& mv, float* X) {
        unsigned hw[8] = { mv.x & 0x3FFu, (mv.x >> 16) & 0x3FFu,
                           mv.y & 0x3FFu, (mv.y >> 16) & 0x3FFu,
                           mv.z & 0x3FFu, (mv.z >> 16) & 0x3FFu,
                           mv.w & 0x3FFu, (mv.w >> 16) & 0x3FFu };
#pragma unroll
        for (int u = 0; u < 8; ++u)
            X[u] = D[hw[u] * 22 + rr];
    };

    // 4-deep mask prefetch ring
    uint4 mB = *(const uint4*)(sm + 8);
    uint4 mC = *(const uint4*)(sm + 16);
    uint4 mD = *(const uint4*)(sm + 24);
    float Xc[8], Xn[8], Pc[8], Pn[8];
    { uint4 m0 = *(const uint4*)(sm); xlook(m0, Xc); }
#pragma unroll
    for (int u = 0; u < 8; ++u) { Pc[u] = 0.f; Pn[u] = 0.f; }

    float v = 0.f, cur = 0.f;
    unsigned zmask = 0;
    float uc = 0.f, oc = 0.f, accs = 0.f;

    for (int gr = 0; gr < 32; ++gr) {
        int nb = gr + 4; if (nb > 31) nb = 31;
        uint4 mE = *(const uint4*)(sm + (size_t)nb * 8);
        xlook(mB, Xn);                  // x_in for next group (off-chain, 3 groups slack)
        unsigned zs[8];
#pragma unroll
        for (int u = 0; u < 8; ++u) {
            // rec dot: ONE ds_read from the direct table
            float rec = D[zmask * 22 + rrec];
            float ij = (cur + Xc[u]) + rec;
            float vd = v + 0.1f * (ij - v);     // bit-exact form (matches reference)
            cur = ij - 0.2f * ij;               // bit-exact form
            bool zb = vd > 0.2f;                // b_dec == VTH exactly
            unsigned long long bal = __ballot(zb);
            v = zb ? 0.f : vd;
            zmask = (unsigned)(bal >> shq) & 0x3FFu;
            zs[u] = zmask;
        }
        if (gr >= 21) {                        // classifier-input lookups (batched)
#pragma unroll
            for (int u = 0; u < 8; ++u)
                Pn[u] = D[zs[u] * 22 + rr];
        }
        if (gr >= 22) {                        // classifier LIF for group gr-1
            bool in = (gr >= 25);              // live groups are 24..31
#pragma unroll
            for (int u = 0; u < 8; ++u) {
                float ci = Pc[u] + bcl;
                uc = (oc > 0.5f) ? ci : fmaf(0.25f, uc, ci);
                oc = (uc > 0.2f) ? 1.f : 0.f;
                if (in) accs += oc;
            }
        }
#pragma unroll
        for (int u = 0; u < 8; ++u) { Xc[u] = Xn[u]; Pc[u] = Pn[u]; }
        mB = mC; mC = mD; mD = mE;
    }
    // epilogue: classifier for group 31 (live)
#pragma unroll
    for (int u = 0; u < 8; ++u) {
        float ci = Pc[u] + bcl;
        uc = (oc > 0.5f) ? ci : fmaf(0.25f, uc, ci);
        oc = (uc > 0.2f) ? 1.f : 0.f;
        accs += oc;
    }
    if (r == 10 || r == 11)
        atomicAdd(&out[b * 2 + (r - 10)], accs * (1.0f / 8192.0f));
}

// ---------------------------------------------------------------------------
extern "C" void kernel_launch(void* const* d_in, const int* in_sizes, int n_in,
                              void* d_out, int out_size, void* d_ws, size_t ws_size,
                              hipStream_t stream) {
    const float* x       = (const float*)d_in[0];
    const float* w_front = (const float*)d_in[1];
    const float* b_front = (const float*)d_in[2];
    const float* w_in    = (const float*)d_in[3];
    const float* w_rec   = (const float*)d_in[4];
    const float* w_cls   = (const float*)d_in[5];
    const float* b_cls   = (const float*)d_in[6];
    float* out = (float*)d_out;

    unsigned short* smask = (unsigned short*)d_ws;   // 64*8384*2 = 1.07 MB (y eliminated)

    k_front_lif<<<dim3(8, BATCH), 256, 0, stream>>>(x, w_front, b_front, smask, out);
    k_lsnn<<<dim3(256), 512, (1536 + 1024 * 22) * sizeof(float), stream>>>(
        smask, w_in, w_rec, w_cls, b_cls, out);
}